// Round 10
// baseline (350.905 us; speedup 1.0000x reference)
//
#include <hip/hip_runtime.h>
#include <hip/hip_bf16.h>

typedef short bf16x8 __attribute__((ext_vector_type(8)));
typedef float f32x4  __attribute__((ext_vector_type(4)));

#define H_NODE 64
#define H_EDGE 128
#define IN_DIM 256
#define WAVES  8
#define BLOCK  512
#define GRID   256
#define LN_EPS 1e-5f

// Static LDS layout (byte offsets), 128 KiB (1 block/CU):
//   [0,      65536): W1^T bf16: addr = col*512 + ((k*2) ^ ((col&7)<<4)),  col in [0,128), k in [0,256)
//   [65536,  98304): W2^T bf16: addr = 65536 + col*256 + ((k*2) ^ ((col&7)<<4)), k in [0,128)
//   [98304, 131072): per-wave transpose tile (16 rows x 128 bf16, 4KB x 8 waves)
//
// Round-10: r9 champion (261.5us: r3 + NT stores) + W2 REGISTER HOISTING.
// Counter-backed rationale: VGPR_Count=128 + 64 AGPR = 192/256 unified -> 64
// registers FREE; LDS pipe (~60-68% busy) is the top shared resource and its
// largest term is the 96 loop-invariant weight ds_read_b128 per wave-tile.
// Edits (register-budget-neutral):
//  (1) preload 16 W2 fragments (t=0,1 x n=0..7; 64 VGPR) once after the
//      staging barrier -- per-lane loop-invariant; GEMM2 reads only t=2,3
//      from LDS. Weight reads/tile: 96 -> 80 (-17% LDS-pipe work).
//  (2) fund it: persistent bias/gamma/beta f32 regs (32) -> per-tile reloads
//      (r2/r5-proven: b1 under GEMM1 cover, LN consts after GEMM2; L1-hot).
// Everything else byte-identical to r9 (staging, swizzles, NT stores).
// Spill tripwire: WRITE_SIZE > 620 MB -> final answer is r9.

static __device__ __forceinline__ short f2bf(float x) {
    __hip_bfloat16 h = __float2bfloat16(x);   // RNE
    return *reinterpret_cast<short*>(&h);
}

static __device__ __forceinline__ float bf2f(short s) {
    union { unsigned int u; float f; } v;
    v.u = ((unsigned int)(unsigned short)s) << 16;
    return v.f;
}

static __device__ __forceinline__ int tswz(int r, int g) {
    return r * 256 + ((g ^ ((r >> 2) << 1)) << 4);
}

static __device__ __forceinline__ bf16x8 cvt8(f32x4 lo, f32x4 hi) {
    bf16x8 f;
    f[0] = f2bf(lo[0]); f[1] = f2bf(lo[1]); f[2] = f2bf(lo[2]); f[3] = f2bf(lo[3]);
    f[4] = f2bf(hi[0]); f[5] = f2bf(hi[1]); f[6] = f2bf(hi[2]); f[7] = f2bf(hi[3]);
    return f;
}

extern "C" __global__ void __launch_bounds__(BLOCK, 2)
edge_update(const float* __restrict__ node,
            const float* __restrict__ edgef,
            const int* __restrict__ ei,          // int32 on device
            const float* __restrict__ W1, const float* __restrict__ b1,
            const float* __restrict__ W2, const float* __restrict__ b2,
            const float* __restrict__ gamma, const float* __restrict__ beta,
            float* __restrict__ out, int E)
{
    __shared__ char lds[131072];
    const int tid = threadIdx.x;

    // ---- stage W1^T (bf16, swizzled) ----
    #pragma unroll 4
    for (int i = 0; i < 64; ++i) {
        int e = tid + i * BLOCK;            // e < 32768; W1 is [k][n], k<256, n<128
        int k = e >> 7, n = e & 127;
        float v = W1[e];
        int addr = n * 512 + ((k * 2) ^ ((n & 7) << 4));
        *(short*)(lds + addr) = f2bf(v);
    }
    // ---- stage W2^T ----
    #pragma unroll 4
    for (int i = 0; i < 32; ++i) {
        int e = tid + i * BLOCK;            // e < 16384; W2 is [k][n], k<128, n<128
        int k = e >> 7, n = e & 127;
        float v = W2[e];
        int addr = 65536 + n * 256 + ((k * 2) ^ ((n & 7) << 4));
        *(short*)(lds + addr) = f2bf(v);
    }
    __syncthreads();

    const int wid   = tid >> 6;
    const int lane  = tid & 63;
    const int lrow  = lane & 15;   // A-frag row / C col / B col
    const int lk8   = lane >> 4;   // k-subchunk 0..3
    const int hbase = 98304 + wid * 4096;
    const int rsw   = (lrow & 7) << 4;   // weight swizzle: ((n*16+lrow)&7)<<4, n-independent

    // ---- hoist W2 fragments t=0,1 (per-lane loop-invariant; 64 VGPR) ----
    bf16x8 W2r0[8], W2r1[8];
    #pragma unroll
    for (int n = 0; n < 8; ++n) {
        const int cb = 65536 + (n * 16 + lrow) * 256;
        W2r0[n] = *(const bf16x8*)(lds + cb + ((0 * 64 + lk8 * 16) ^ rsw));
        W2r1[n] = *(const bf16x8*)(lds + cb + ((1 * 64 + lk8 * 16) ^ rsw));
    }

    const int ntiles  = (E + 15) >> 4;
    const int wstride = GRID * WAVES;

    int tile = blockIdx.x * WAVES + wid;
    if (tile >= ntiles) return;

    // ---- prologue: indices + staged gather for tile t; indices for t+1 ----
    int rowg = tile * 16 + lrow; if (rowg >= E) rowg = E - 1;
    int sidx = ei[rowg];
    int didx = ei[E + rowg];

    f32x4 Sn0, Sn1, Sn2, Sn3, Sn4, Sn5, Sn6, Sn7;   // node src/dst raw
    f32x4 Se0, Se1, Se2, Se3, Se4, Se5, Se6, Se7;   // edge row raw
    {
        const float* sp = node + (size_t)sidx * H_NODE + lk8 * 8;
        const float* dp = node + (size_t)didx * H_NODE + lk8 * 8;
        const float* ep = edgef + (size_t)rowg * H_EDGE + lk8 * 8;
        Sn0 = *(const f32x4*)(sp);      Sn1 = *(const f32x4*)(sp + 4);
        Sn2 = *(const f32x4*)(sp + 32); Sn3 = *(const f32x4*)(sp + 36);
        Sn4 = *(const f32x4*)(dp);      Sn5 = *(const f32x4*)(dp + 4);
        Sn6 = *(const f32x4*)(dp + 32); Sn7 = *(const f32x4*)(dp + 36);
        Se0 = *(const f32x4*)(ep);      Se1 = *(const f32x4*)(ep + 4);
        Se2 = *(const f32x4*)(ep + 32); Se3 = *(const f32x4*)(ep + 36);
        Se4 = *(const f32x4*)(ep + 64); Se5 = *(const f32x4*)(ep + 68);
        Se6 = *(const f32x4*)(ep + 96); Se7 = *(const f32x4*)(ep + 100);
    }
    int next  = tile + wstride;
    int nrowg = next * 16 + lrow; if (nrowg >= E) nrowg = E - 1;
    int nsidx = ei[nrowg];
    int ndidx = ei[E + nrowg];

    while (tile < ntiles) {
        // ---- fold staged gather (issued one full tile ago) into A1 ----
        bf16x8 A1[8];
        A1[0] = cvt8(Sn0, Sn1);
        A1[1] = cvt8(Sn2, Sn3);
        A1[2] = cvt8(Sn4, Sn5);
        A1[3] = cvt8(Sn6, Sn7);
        A1[4] = cvt8(Se0, Se1);
        A1[5] = cvt8(Se2, Se3);
        A1[6] = cvt8(Se4, Se5);
        A1[7] = cvt8(Se6, Se7);

        // ---- issue NEXT tile's FULL gather burst (in flight all tile) ----
        {
            const float* sp = node + (size_t)nsidx * H_NODE + lk8 * 8;
            const float* dp = node + (size_t)ndidx * H_NODE + lk8 * 8;
            const float* ep = edgef + (size_t)nrowg * H_EDGE + lk8 * 8;
            Sn0 = *(const f32x4*)(sp);      Sn1 = *(const f32x4*)(sp + 4);
            Sn2 = *(const f32x4*)(sp + 32); Sn3 = *(const f32x4*)(sp + 36);
            Sn4 = *(const f32x4*)(dp);      Sn5 = *(const f32x4*)(dp + 4);
            Sn6 = *(const f32x4*)(dp + 32); Sn7 = *(const f32x4*)(dp + 36);
            Se0 = *(const f32x4*)(ep);      Se1 = *(const f32x4*)(ep + 4);
            Se2 = *(const f32x4*)(ep + 32); Se3 = *(const f32x4*)(ep + 36);
            Se4 = *(const f32x4*)(ep + 64); Se5 = *(const f32x4*)(ep + 68);
            Se6 = *(const f32x4*)(ep + 96); Se7 = *(const f32x4*)(ep + 100);
        }
        // ---- prefetch tile+2 indices ----
        int t2 = next + wstride;
        int t2rowg = t2 * 16 + lrow; if (t2rowg >= E) t2rowg = E - 1;
        int t2s = ei[t2rowg];
        int t2d = ei[E + t2rowg];

        // ---- b1 reload (L1-hot broadcast lines; latency covered by GEMM1) ----
        float b1v[8];
        #pragma unroll
        for (int n = 0; n < 8; ++n) b1v[n] = b1[n * 16 + lrow];

        // ---- GEMM1: [16x256] @ [256x128] ----
        f32x4 acc[8];
        #pragma unroll
        for (int n = 0; n < 8; ++n) acc[n] = (f32x4){0.f, 0.f, 0.f, 0.f};
        #pragma unroll
        for (int n = 0; n < 8; ++n) {
            const int cb  = (n * 16 + lrow) * 512;
            #pragma unroll
            for (int t = 0; t < 8; ++t) {
                int kb = t * 64 + lk8 * 16;
                bf16x8 bfrag = *(const bf16x8*)(lds + cb + (kb ^ rsw));
                acc[n] = __builtin_amdgcn_mfma_f32_16x16x32_bf16(A1[t], bfrag, acc[n], 0, 0, 0);
            }
        }

        // ---- bias + relu -> h (bf16) to per-wave LDS (conflict-free swizzle) ----
        #pragma unroll
        for (int n = 0; n < 8; ++n) {
            const int g = n * 2 + (lrow >> 3);
            const int cl = (lrow & 7) * 2;
            #pragma unroll
            for (int i = 0; i < 4; ++i) {
                float u = fmaxf(acc[n][i] + b1v[n], 0.f);
                int row = lk8 * 4 + i;
                *(short*)(lds + hbase + tswz(row, g) + cl) = f2bf(u);
            }
        }
        // same-wave cross-lane LDS visibility: drain ds_writes before reads
        asm volatile("s_waitcnt lgkmcnt(0)" ::: "memory");

        // ---- GEMM2: [16x128] @ [128x128]; t=0,1 from registers, t=2,3 from LDS ----
        bf16x8 A2[4];
        #pragma unroll
        for (int t = 0; t < 4; ++t)
            A2[t] = *(const bf16x8*)(lds + hbase + tswz(lrow, t * 4 + lk8));

        f32x4 acc2[8];
        #pragma unroll
        for (int n = 0; n < 8; ++n) acc2[n] = (f32x4){0.f, 0.f, 0.f, 0.f};
        #pragma unroll
        for (int n = 0; n < 8; ++n) {
            const int cb  = 65536 + (n * 16 + lrow) * 256;
            acc2[n] = __builtin_amdgcn_mfma_f32_16x16x32_bf16(A2[0], W2r0[n], acc2[n], 0, 0, 0);
            acc2[n] = __builtin_amdgcn_mfma_f32_16x16x32_bf16(A2[1], W2r1[n], acc2[n], 0, 0, 0);
            #pragma unroll
            for (int t = 2; t < 4; ++t) {
                int kb = t * 64 + lk8 * 16;
                bf16x8 bfrag = *(const bf16x8*)(lds + cb + (kb ^ rsw));
                acc2[n] = __builtin_amdgcn_mfma_f32_16x16x32_bf16(A2[t], bfrag, acc2[n], 0, 0, 0);
            }
        }

        // ---- LN constants reload (L1-hot, once per tile) ----
        float b2v[8], gv[8], btv[8];
        #pragma unroll
        for (int n = 0; n < 8; ++n) {
            int c = n * 16 + lrow;
            b2v[n] = b2[c]; gv[n] = gamma[c]; btv[n] = beta[c];
        }

        // ---- bias2 + LayerNorm (C-layout) -> w (bf16) back through LDS ----
        #pragma unroll
        for (int i = 0; i < 4; ++i) {
            float u[8];
            float s = 0.f, sq = 0.f;
            #pragma unroll
            for (int n = 0; n < 8; ++n) {
                u[n] = acc2[n][i] + b2v[n];
                s  += u[n];
                sq += u[n] * u[n];
            }
            #pragma unroll
            for (int m = 1; m < 16; m <<= 1) {
                s  += __shfl_xor(s,  m, 64);
                sq += __shfl_xor(sq, m, 64);
            }
            float mu  = s * (1.f / 128.f);
            float var = sq * (1.f / 128.f) - mu * mu;
            float rs  = rsqrtf(var + LN_EPS);
            int row = lk8 * 4 + i;
            const int cl = (lrow & 7) * 2;
            #pragma unroll
            for (int n = 0; n < 8; ++n) {
                float w = (u[n] - mu) * rs * gv[n] + btv[n];
                *(short*)(lds + hbase + tswz(row, n * 2 + (lrow >> 3)) + cl) = f2bf(w);
            }
        }
        asm volatile("s_waitcnt lgkmcnt(0)" ::: "memory");

        // ---- read w in A-layout, residual from registers, coalesced NT store ----
        {
            int row = tile * 16 + lrow;
            if (row < E) {
                float* orow = out + (size_t)row * H_EDGE;
                #pragma unroll
                for (int t = 0; t < 4; ++t) {
                    bf16x8 wf = *(const bf16x8*)(lds + hbase + tswz(lrow, t * 4 + lk8));
                    bf16x8 ef = A1[t + 4];
                    f32x4 lo, hi;
                    lo[0] = bf2f(wf[0]) + bf2f(ef[0]);
                    lo[1] = bf2f(wf[1]) + bf2f(ef[1]);
                    lo[2] = bf2f(wf[2]) + bf2f(ef[2]);
                    lo[3] = bf2f(wf[3]) + bf2f(ef[3]);
                    hi[0] = bf2f(wf[4]) + bf2f(ef[4]);
                    hi[1] = bf2f(wf[5]) + bf2f(ef[5]);
                    hi[2] = bf2f(wf[6]) + bf2f(ef[6]);
                    hi[3] = bf2f(wf[7]) + bf2f(ef[7]);
                    float* dst = orow + t * 32 + lk8 * 8;
                    __builtin_nontemporal_store(lo, (f32x4*)dst);
                    __builtin_nontemporal_store(hi, (f32x4*)(dst + 4));
                }
            }
        }

        // ---- rotate pipeline state ----
        tile = next;  next = t2;
        nrowg = t2rowg; nsidx = t2s; ndidx = t2d;
    }
}

extern "C" void kernel_launch(void* const* d_in, const int* in_sizes, int n_in,
                              void* d_out, int out_size, void* d_ws, size_t ws_size,
                              hipStream_t stream) {
    const float* node  = (const float*)d_in[0];
    const float* edgef = (const float*)d_in[1];
    const int*   ei    = (const int*)d_in[2];    // int32 on device
    const float* W1    = (const float*)d_in[3];
    const float* b1    = (const float*)d_in[4];
    const float* W2    = (const float*)d_in[5];
    const float* b2    = (const float*)d_in[6];
    const float* gamma = (const float*)d_in[7];
    const float* beta  = (const float*)d_in[8];
    float* outp = (float*)d_out;
    const int E = in_sizes[2] / 2;   // edge_index is [2, E]

    hipLaunchKernelGGL(edge_update, dim3(GRID), dim3(BLOCK), 0, stream,
                       node, edgef, ei, W1, b1, W2, b2, gamma, beta, outp, E);
}

// Round 11
// 270.865 us; speedup vs baseline: 1.2955x; 1.2955x over previous
//
#include <hip/hip_runtime.h>
#include <hip/hip_bf16.h>

typedef short bf16x8 __attribute__((ext_vector_type(8)));
typedef float f32x4  __attribute__((ext_vector_type(4)));

#define H_NODE 64
#define H_EDGE 128
#define IN_DIM 256
#define WAVES  8
#define BLOCK  512
#define GRID   256
#define LN_EPS 1e-5f

// Static LDS layout (byte offsets), 128 KiB (1 block/CU):
//   [0,      65536): W1^T bf16: addr = col*512 + ((k*2) ^ ((col&7)<<4)),  col in [0,128), k in [0,256)
//   [65536,  98304): W2^T bf16: addr = 65536 + col*256 + ((k*2) ^ ((col&7)<<4)), k in [0,128)
//   [98304, 131072): per-wave transpose tile (16 rows x 128 bf16, 4KB x 8 waves)
//
// Round-11: REVERT to r9 champion (261.5us) + T5 s_setprio around MFMA clusters.
// r10 falsified the LDS-read model: hoisting W2 cut bank-conflicts -12% but
// cost +34% time via register-pressure side effects (arch VGPR pinned at 128,
// gather-staging schedule destroyed). Constraint set after 10 rounds:
//   - HBM bytes not binding (r9: -18% bytes -> -0.4% time)
//   - LDS reads not binding (r10)
//   - wave count capped by the 96-reg staging envelope (r5/r7 spills)
//   => wall is per-SIMD issue + serial chain at 2 waves/SIMD.
// T5 is the only zero-register lever for issue arbitration; its regime
// (independent non-barrier waves per SIMD, MFMA cluster vs VALU phase) matches
// this kernel exactly (attn-like: +4-7% documented; null only in lockstep).
// Everything else is r9 byte-identical. Final answer = faster of {this, r9}.

static __device__ __forceinline__ short f2bf(float x) {
    __hip_bfloat16 h = __float2bfloat16(x);   // RNE
    return *reinterpret_cast<short*>(&h);
}

static __device__ __forceinline__ float bf2f(short s) {
    union { unsigned int u; float f; } v;
    v.u = ((unsigned int)(unsigned short)s) << 16;
    return v.f;
}

static __device__ __forceinline__ int tswz(int r, int g) {
    return r * 256 + ((g ^ ((r >> 2) << 1)) << 4);
}

static __device__ __forceinline__ bf16x8 cvt8(f32x4 lo, f32x4 hi) {
    bf16x8 f;
    f[0] = f2bf(lo[0]); f[1] = f2bf(lo[1]); f[2] = f2bf(lo[2]); f[3] = f2bf(lo[3]);
    f[4] = f2bf(hi[0]); f[5] = f2bf(hi[1]); f[6] = f2bf(hi[2]); f[7] = f2bf(hi[3]);
    return f;
}

extern "C" __global__ void __launch_bounds__(BLOCK, 2)
edge_update(const float* __restrict__ node,
            const float* __restrict__ edgef,
            const int* __restrict__ ei,          // int32 on device
            const float* __restrict__ W1, const float* __restrict__ b1,
            const float* __restrict__ W2, const float* __restrict__ b2,
            const float* __restrict__ gamma, const float* __restrict__ beta,
            float* __restrict__ out, int E)
{
    __shared__ char lds[131072];
    const int tid = threadIdx.x;

    // ---- stage W1^T (bf16, swizzled) ----
    #pragma unroll 4
    for (int i = 0; i < 64; ++i) {
        int e = tid + i * BLOCK;            // e < 32768; W1 is [k][n], k<256, n<128
        int k = e >> 7, n = e & 127;
        float v = W1[e];
        int addr = n * 512 + ((k * 2) ^ ((n & 7) << 4));
        *(short*)(lds + addr) = f2bf(v);
    }
    // ---- stage W2^T ----
    #pragma unroll 4
    for (int i = 0; i < 32; ++i) {
        int e = tid + i * BLOCK;            // e < 16384; W2 is [k][n], k<128, n<128
        int k = e >> 7, n = e & 127;
        float v = W2[e];
        int addr = 65536 + n * 256 + ((k * 2) ^ ((n & 7) << 4));
        *(short*)(lds + addr) = f2bf(v);
    }
    __syncthreads();

    const int wid   = tid >> 6;
    const int lane  = tid & 63;
    const int lrow  = lane & 15;   // A-frag row / C col / B col
    const int lk8   = lane >> 4;   // k-subchunk 0..3
    const int hbase = 98304 + wid * 4096;

    // per-lane column constants (persistent; plenty of regs at 2 waves/SIMD)
    float bias1[8], bias2[8], g8[8], bt8[8];
    #pragma unroll
    for (int n = 0; n < 8; ++n) {
        int c = n * 16 + lrow;
        bias1[n] = b1[c]; bias2[n] = b2[c]; g8[n] = gamma[c]; bt8[n] = beta[c];
    }

    const int ntiles  = (E + 15) >> 4;
    const int wstride = GRID * WAVES;

    int tile = blockIdx.x * WAVES + wid;
    if (tile >= ntiles) return;

    // ---- prologue: indices + staged gather for tile t; indices for t+1 ----
    int rowg = tile * 16 + lrow; if (rowg >= E) rowg = E - 1;
    int sidx = ei[rowg];
    int didx = ei[E + rowg];

    f32x4 Sn0, Sn1, Sn2, Sn3, Sn4, Sn5, Sn6, Sn7;   // node src/dst raw
    f32x4 Se0, Se1, Se2, Se3, Se4, Se5, Se6, Se7;   // edge row raw
    {
        const float* sp = node + (size_t)sidx * H_NODE + lk8 * 8;
        const float* dp = node + (size_t)didx * H_NODE + lk8 * 8;
        const float* ep = edgef + (size_t)rowg * H_EDGE + lk8 * 8;
        Sn0 = *(const f32x4*)(sp);      Sn1 = *(const f32x4*)(sp + 4);
        Sn2 = *(const f32x4*)(sp + 32); Sn3 = *(const f32x4*)(sp + 36);
        Sn4 = *(const f32x4*)(dp);      Sn5 = *(const f32x4*)(dp + 4);
        Sn6 = *(const f32x4*)(dp + 32); Sn7 = *(const f32x4*)(dp + 36);
        Se0 = *(const f32x4*)(ep);      Se1 = *(const f32x4*)(ep + 4);
        Se2 = *(const f32x4*)(ep + 32); Se3 = *(const f32x4*)(ep + 36);
        Se4 = *(const f32x4*)(ep + 64); Se5 = *(const f32x4*)(ep + 68);
        Se6 = *(const f32x4*)(ep + 96); Se7 = *(const f32x4*)(ep + 100);
    }
    int next  = tile + wstride;
    int nrowg = next * 16 + lrow; if (nrowg >= E) nrowg = E - 1;
    int nsidx = ei[nrowg];
    int ndidx = ei[E + nrowg];

    while (tile < ntiles) {
        // ---- fold staged gather (issued one full tile ago) into A1 ----
        bf16x8 A1[8];
        A1[0] = cvt8(Sn0, Sn1);
        A1[1] = cvt8(Sn2, Sn3);
        A1[2] = cvt8(Sn4, Sn5);
        A1[3] = cvt8(Sn6, Sn7);
        A1[4] = cvt8(Se0, Se1);
        A1[5] = cvt8(Se2, Se3);
        A1[6] = cvt8(Se4, Se5);
        A1[7] = cvt8(Se6, Se7);

        // ---- issue NEXT tile's FULL gather burst (in flight all tile) ----
        {
            const float* sp = node + (size_t)nsidx * H_NODE + lk8 * 8;
            const float* dp = node + (size_t)ndidx * H_NODE + lk8 * 8;
            const float* ep = edgef + (size_t)nrowg * H_EDGE + lk8 * 8;
            Sn0 = *(const f32x4*)(sp);      Sn1 = *(const f32x4*)(sp + 4);
            Sn2 = *(const f32x4*)(sp + 32); Sn3 = *(const f32x4*)(sp + 36);
            Sn4 = *(const f32x4*)(dp);      Sn5 = *(const f32x4*)(dp + 4);
            Sn6 = *(const f32x4*)(dp + 32); Sn7 = *(const f32x4*)(dp + 36);
            Se0 = *(const f32x4*)(ep);      Se1 = *(const f32x4*)(ep + 4);
            Se2 = *(const f32x4*)(ep + 32); Se3 = *(const f32x4*)(ep + 36);
            Se4 = *(const f32x4*)(ep + 64); Se5 = *(const f32x4*)(ep + 68);
            Se6 = *(const f32x4*)(ep + 96); Se7 = *(const f32x4*)(ep + 100);
        }
        // ---- prefetch tile+2 indices ----
        int t2 = next + wstride;
        int t2rowg = t2 * 16 + lrow; if (t2rowg >= E) t2rowg = E - 1;
        int t2s = ei[t2rowg];
        int t2d = ei[E + t2rowg];

        // ---- GEMM1: [16x256] @ [256x128]  (T5: boost MFMA cluster) ----
        f32x4 acc[8];
        #pragma unroll
        for (int n = 0; n < 8; ++n) acc[n] = (f32x4){0.f, 0.f, 0.f, 0.f};
        __builtin_amdgcn_s_setprio(1);
        #pragma unroll
        for (int n = 0; n < 8; ++n) {
            const int col = n * 16 + lrow;
            const int cb  = col * 512;
            const int sw  = (col & 7) << 4;
            #pragma unroll
            for (int t = 0; t < 8; ++t) {
                int kb = t * 64 + lk8 * 16;
                bf16x8 bfrag = *(const bf16x8*)(lds + cb + (kb ^ sw));
                acc[n] = __builtin_amdgcn_mfma_f32_16x16x32_bf16(A1[t], bfrag, acc[n], 0, 0, 0);
            }
        }
        __builtin_amdgcn_s_setprio(0);

        // ---- bias + relu -> h (bf16) to per-wave LDS (conflict-free swizzle) ----
        #pragma unroll
        for (int n = 0; n < 8; ++n) {
            const int g = n * 2 + (lrow >> 3);
            const int cl = (lrow & 7) * 2;
            #pragma unroll
            for (int i = 0; i < 4; ++i) {
                float u = fmaxf(acc[n][i] + bias1[n], 0.f);
                int row = lk8 * 4 + i;
                *(short*)(lds + hbase + tswz(row, g) + cl) = f2bf(u);
            }
        }
        // same-wave cross-lane LDS visibility: drain ds_writes before reads
        asm volatile("s_waitcnt lgkmcnt(0)" ::: "memory");

        // ---- GEMM2: [16x128] @ [128x128]  (T5: boost MFMA cluster) ----
        bf16x8 A2[4];
        #pragma unroll
        for (int t = 0; t < 4; ++t)
            A2[t] = *(const bf16x8*)(lds + hbase + tswz(lrow, t * 4 + lk8));

        f32x4 acc2[8];
        #pragma unroll
        for (int n = 0; n < 8; ++n) acc2[n] = (f32x4){0.f, 0.f, 0.f, 0.f};
        __builtin_amdgcn_s_setprio(1);
        #pragma unroll
        for (int n = 0; n < 8; ++n) {
            const int col = n * 16 + lrow;
            const int cb  = 65536 + col * 256;
            const int sw  = (col & 7) << 4;
            #pragma unroll
            for (int t = 0; t < 4; ++t) {
                int kb = t * 64 + lk8 * 16;
                bf16x8 bfrag = *(const bf16x8*)(lds + cb + (kb ^ sw));
                acc2[n] = __builtin_amdgcn_mfma_f32_16x16x32_bf16(A2[t], bfrag, acc2[n], 0, 0, 0);
            }
        }
        __builtin_amdgcn_s_setprio(0);

        // ---- bias2 + LayerNorm (C-layout) -> w (bf16) back through LDS ----
        #pragma unroll
        for (int i = 0; i < 4; ++i) {
            float u[8];
            float s = 0.f, sq = 0.f;
            #pragma unroll
            for (int n = 0; n < 8; ++n) {
                u[n] = acc2[n][i] + bias2[n];
                s  += u[n];
                sq += u[n] * u[n];
            }
            #pragma unroll
            for (int m = 1; m < 16; m <<= 1) {
                s  += __shfl_xor(s,  m, 64);
                sq += __shfl_xor(sq, m, 64);
            }
            float mu  = s * (1.f / 128.f);
            float var = sq * (1.f / 128.f) - mu * mu;
            float rs  = rsqrtf(var + LN_EPS);
            int row = lk8 * 4 + i;
            const int cl = (lrow & 7) * 2;
            #pragma unroll
            for (int n = 0; n < 8; ++n) {
                float w = (u[n] - mu) * rs * g8[n] + bt8[n];
                *(short*)(lds + hbase + tswz(row, n * 2 + (lrow >> 3)) + cl) = f2bf(w);
            }
        }
        asm volatile("s_waitcnt lgkmcnt(0)" ::: "memory");

        // ---- read w in A-layout, residual from registers, coalesced NT store ----
        {
            int row = tile * 16 + lrow;
            if (row < E) {
                float* orow = out + (size_t)row * H_EDGE;
                #pragma unroll
                for (int t = 0; t < 4; ++t) {
                    bf16x8 wf = *(const bf16x8*)(lds + hbase + tswz(lrow, t * 4 + lk8));
                    bf16x8 ef = A1[t + 4];
                    f32x4 lo, hi;
                    lo[0] = bf2f(wf[0]) + bf2f(ef[0]);
                    lo[1] = bf2f(wf[1]) + bf2f(ef[1]);
                    lo[2] = bf2f(wf[2]) + bf2f(ef[2]);
                    lo[3] = bf2f(wf[3]) + bf2f(ef[3]);
                    hi[0] = bf2f(wf[4]) + bf2f(ef[4]);
                    hi[1] = bf2f(wf[5]) + bf2f(ef[5]);
                    hi[2] = bf2f(wf[6]) + bf2f(ef[6]);
                    hi[3] = bf2f(wf[7]) + bf2f(ef[7]);
                    float* dst = orow + t * 32 + lk8 * 8;
                    __builtin_nontemporal_store(lo, (f32x4*)dst);
                    __builtin_nontemporal_store(hi, (f32x4*)(dst + 4));
                }
            }
        }

        // ---- rotate pipeline state ----
        tile = next;  next = t2;
        nrowg = t2rowg; nsidx = t2s; ndidx = t2d;
    }
}

extern "C" void kernel_launch(void* const* d_in, const int* in_sizes, int n_in,
                              void* d_out, int out_size, void* d_ws, size_t ws_size,
                              hipStream_t stream) {
    const float* node  = (const float*)d_in[0];
    const float* edgef = (const float*)d_in[1];
    const int*   ei    = (const int*)d_in[2];    // int32 on device
    const float* W1    = (const float*)d_in[3];
    const float* b1    = (const float*)d_in[4];
    const float* W2    = (const float*)d_in[5];
    const float* b2    = (const float*)d_in[6];
    const float* gamma = (const float*)d_in[7];
    const float* beta  = (const float*)d_in[8];
    float* outp = (float*)d_out;
    const int E = in_sizes[2] / 2;   // edge_index is [2, E]

    hipLaunchKernelGGL(edge_update, dim3(GRID), dim3(BLOCK), 0, stream,
                       node, edgef, ei, W1, b1, W2, b2, gamma, beta, outp, E);
}

// Round 12
// 262.490 us; speedup vs baseline: 1.3368x; 1.0319x over previous
//
#include <hip/hip_runtime.h>
#include <hip/hip_bf16.h>

typedef short bf16x8 __attribute__((ext_vector_type(8)));
typedef float f32x4  __attribute__((ext_vector_type(4)));

#define H_NODE 64
#define H_EDGE 128
#define IN_DIM 256
#define WAVES  8
#define BLOCK  512
#define GRID   256
#define LN_EPS 1e-5f

// FINAL (round-12) = round-9 champion, byte-identical. 261.5us measured.
//
// Structure: 8 waves x 256 VGPR (1 block/CU via 128KiB LDS), full 1-tile-deep
// register staging of all gathers (96 VGPR in flight across the whole tile),
// MFMA GEMM1/GEMM2 with swizzled LDS-resident bf16 weights, h and w transposed
// through a per-wave 4KB LDS tile, register-resident residual, non-temporal
// f32 output stores (kills write-allocate RMW: FETCH 642->468 MB).
//
// Bracketing evidence from the session (what NOT to change):
//  - NT loads on edgef: +7us (r8) -- L3 assist matters for the stream.
//  - W2-fragment register hoisting: +89us (r10) -- any extra persistent
//    VGPRs destroy the staging schedule at the 256-reg envelope.
//  - 12/16-wave variants: spills (r1/r5); row-pairing: spills (r7);
//    swapped-operand MFMA: longer serial chain (r6); s_setprio: -9us (r11);
//    late stream re-reads: L2 lifetime < 1 tile (r4).
// Remaining gap to the ~164us byte-floor is per-SIMD issue + serial-chain
// latency at 2 waves/SIMD -- structural at this occupancy point.

static __device__ __forceinline__ short f2bf(float x) {
    __hip_bfloat16 h = __float2bfloat16(x);   // RNE
    return *reinterpret_cast<short*>(&h);
}

static __device__ __forceinline__ float bf2f(short s) {
    union { unsigned int u; float f; } v;
    v.u = ((unsigned int)(unsigned short)s) << 16;
    return v.f;
}

static __device__ __forceinline__ int tswz(int r, int g) {
    return r * 256 + ((g ^ ((r >> 2) << 1)) << 4);
}

static __device__ __forceinline__ bf16x8 cvt8(f32x4 lo, f32x4 hi) {
    bf16x8 f;
    f[0] = f2bf(lo[0]); f[1] = f2bf(lo[1]); f[2] = f2bf(lo[2]); f[3] = f2bf(lo[3]);
    f[4] = f2bf(hi[0]); f[5] = f2bf(hi[1]); f[6] = f2bf(hi[2]); f[7] = f2bf(hi[3]);
    return f;
}

extern "C" __global__ void __launch_bounds__(BLOCK, 2)
edge_update(const float* __restrict__ node,
            const float* __restrict__ edgef,
            const int* __restrict__ ei,          // int32 on device
            const float* __restrict__ W1, const float* __restrict__ b1,
            const float* __restrict__ W2, const float* __restrict__ b2,
            const float* __restrict__ gamma, const float* __restrict__ beta,
            float* __restrict__ out, int E)
{
    __shared__ char lds[131072];
    const int tid = threadIdx.x;

    // ---- stage W1^T (bf16, swizzled) ----
    #pragma unroll 4
    for (int i = 0; i < 64; ++i) {
        int e = tid + i * BLOCK;            // e < 32768; W1 is [k][n], k<256, n<128
        int k = e >> 7, n = e & 127;
        float v = W1[e];
        int addr = n * 512 + ((k * 2) ^ ((n & 7) << 4));
        *(short*)(lds + addr) = f2bf(v);
    }
    // ---- stage W2^T ----
    #pragma unroll 4
    for (int i = 0; i < 32; ++i) {
        int e = tid + i * BLOCK;            // e < 16384; W2 is [k][n], k<128, n<128
        int k = e >> 7, n = e & 127;
        float v = W2[e];
        int addr = 65536 + n * 256 + ((k * 2) ^ ((n & 7) << 4));
        *(short*)(lds + addr) = f2bf(v);
    }
    __syncthreads();

    const int wid   = tid >> 6;
    const int lane  = tid & 63;
    const int lrow  = lane & 15;   // A-frag row / C col / B col
    const int lk8   = lane >> 4;   // k-subchunk 0..3
    const int hbase = 98304 + wid * 4096;

    // per-lane column constants (persistent; plenty of regs at 2 waves/SIMD)
    float bias1[8], bias2[8], g8[8], bt8[8];
    #pragma unroll
    for (int n = 0; n < 8; ++n) {
        int c = n * 16 + lrow;
        bias1[n] = b1[c]; bias2[n] = b2[c]; g8[n] = gamma[c]; bt8[n] = beta[c];
    }

    const int ntiles  = (E + 15) >> 4;
    const int wstride = GRID * WAVES;

    int tile = blockIdx.x * WAVES + wid;
    if (tile >= ntiles) return;

    // ---- prologue: indices + staged gather for tile t; indices for t+1 ----
    int rowg = tile * 16 + lrow; if (rowg >= E) rowg = E - 1;
    int sidx = ei[rowg];
    int didx = ei[E + rowg];

    f32x4 Sn0, Sn1, Sn2, Sn3, Sn4, Sn5, Sn6, Sn7;   // node src/dst raw
    f32x4 Se0, Se1, Se2, Se3, Se4, Se5, Se6, Se7;   // edge row raw
    {
        const float* sp = node + (size_t)sidx * H_NODE + lk8 * 8;
        const float* dp = node + (size_t)didx * H_NODE + lk8 * 8;
        const float* ep = edgef + (size_t)rowg * H_EDGE + lk8 * 8;
        Sn0 = *(const f32x4*)(sp);      Sn1 = *(const f32x4*)(sp + 4);
        Sn2 = *(const f32x4*)(sp + 32); Sn3 = *(const f32x4*)(sp + 36);
        Sn4 = *(const f32x4*)(dp);      Sn5 = *(const f32x4*)(dp + 4);
        Sn6 = *(const f32x4*)(dp + 32); Sn7 = *(const f32x4*)(dp + 36);
        Se0 = *(const f32x4*)(ep);      Se1 = *(const f32x4*)(ep + 4);
        Se2 = *(const f32x4*)(ep + 32); Se3 = *(const f32x4*)(ep + 36);
        Se4 = *(const f32x4*)(ep + 64); Se5 = *(const f32x4*)(ep + 68);
        Se6 = *(const f32x4*)(ep + 96); Se7 = *(const f32x4*)(ep + 100);
    }
    int next  = tile + wstride;
    int nrowg = next * 16 + lrow; if (nrowg >= E) nrowg = E - 1;
    int nsidx = ei[nrowg];
    int ndidx = ei[E + nrowg];

    while (tile < ntiles) {
        // ---- fold staged gather (issued one full tile ago) into A1 ----
        bf16x8 A1[8];
        A1[0] = cvt8(Sn0, Sn1);
        A1[1] = cvt8(Sn2, Sn3);
        A1[2] = cvt8(Sn4, Sn5);
        A1[3] = cvt8(Sn6, Sn7);
        A1[4] = cvt8(Se0, Se1);
        A1[5] = cvt8(Se2, Se3);
        A1[6] = cvt8(Se4, Se5);
        A1[7] = cvt8(Se6, Se7);

        // ---- issue NEXT tile's FULL gather burst (in flight all tile) ----
        {
            const float* sp = node + (size_t)nsidx * H_NODE + lk8 * 8;
            const float* dp = node + (size_t)ndidx * H_NODE + lk8 * 8;
            const float* ep = edgef + (size_t)nrowg * H_EDGE + lk8 * 8;
            Sn0 = *(const f32x4*)(sp);      Sn1 = *(const f32x4*)(sp + 4);
            Sn2 = *(const f32x4*)(sp + 32); Sn3 = *(const f32x4*)(sp + 36);
            Sn4 = *(const f32x4*)(dp);      Sn5 = *(const f32x4*)(dp + 4);
            Sn6 = *(const f32x4*)(dp + 32); Sn7 = *(const f32x4*)(dp + 36);
            Se0 = *(const f32x4*)(ep);      Se1 = *(const f32x4*)(ep + 4);
            Se2 = *(const f32x4*)(ep + 32); Se3 = *(const f32x4*)(ep + 36);
            Se4 = *(const f32x4*)(ep + 64); Se5 = *(const f32x4*)(ep + 68);
            Se6 = *(const f32x4*)(ep + 96); Se7 = *(const f32x4*)(ep + 100);
        }
        // ---- prefetch tile+2 indices ----
        int t2 = next + wstride;
        int t2rowg = t2 * 16 + lrow; if (t2rowg >= E) t2rowg = E - 1;
        int t2s = ei[t2rowg];
        int t2d = ei[E + t2rowg];

        // ---- GEMM1: [16x256] @ [256x128] ----
        f32x4 acc[8];
        #pragma unroll
        for (int n = 0; n < 8; ++n) acc[n] = (f32x4){0.f, 0.f, 0.f, 0.f};
        #pragma unroll
        for (int n = 0; n < 8; ++n) {
            const int col = n * 16 + lrow;
            const int cb  = col * 512;
            const int sw  = (col & 7) << 4;
            #pragma unroll
            for (int t = 0; t < 8; ++t) {
                int kb = t * 64 + lk8 * 16;
                bf16x8 bfrag = *(const bf16x8*)(lds + cb + (kb ^ sw));
                acc[n] = __builtin_amdgcn_mfma_f32_16x16x32_bf16(A1[t], bfrag, acc[n], 0, 0, 0);
            }
        }

        // ---- bias + relu -> h (bf16) to per-wave LDS (conflict-free swizzle) ----
        #pragma unroll
        for (int n = 0; n < 8; ++n) {
            const int g = n * 2 + (lrow >> 3);
            const int cl = (lrow & 7) * 2;
            #pragma unroll
            for (int i = 0; i < 4; ++i) {
                float u = fmaxf(acc[n][i] + bias1[n], 0.f);
                int row = lk8 * 4 + i;
                *(short*)(lds + hbase + tswz(row, g) + cl) = f2bf(u);
            }
        }
        // same-wave cross-lane LDS visibility: drain ds_writes before reads
        asm volatile("s_waitcnt lgkmcnt(0)" ::: "memory");

        // ---- GEMM2: [16x128] @ [128x128] ----
        bf16x8 A2[4];
        #pragma unroll
        for (int t = 0; t < 4; ++t)
            A2[t] = *(const bf16x8*)(lds + hbase + tswz(lrow, t * 4 + lk8));

        f32x4 acc2[8];
        #pragma unroll
        for (int n = 0; n < 8; ++n) acc2[n] = (f32x4){0.f, 0.f, 0.f, 0.f};
        #pragma unroll
        for (int n = 0; n < 8; ++n) {
            const int col = n * 16 + lrow;
            const int cb  = 65536 + col * 256;
            const int sw  = (col & 7) << 4;
            #pragma unroll
            for (int t = 0; t < 4; ++t) {
                int kb = t * 64 + lk8 * 16;
                bf16x8 bfrag = *(const bf16x8*)(lds + cb + (kb ^ sw));
                acc2[n] = __builtin_amdgcn_mfma_f32_16x16x32_bf16(A2[t], bfrag, acc2[n], 0, 0, 0);
            }
        }

        // ---- bias2 + LayerNorm (C-layout) -> w (bf16) back through LDS ----
        #pragma unroll
        for (int i = 0; i < 4; ++i) {
            float u[8];
            float s = 0.f, sq = 0.f;
            #pragma unroll
            for (int n = 0; n < 8; ++n) {
                u[n] = acc2[n][i] + bias2[n];
                s  += u[n];
                sq += u[n] * u[n];
            }
            #pragma unroll
            for (int m = 1; m < 16; m <<= 1) {
                s  += __shfl_xor(s,  m, 64);
                sq += __shfl_xor(sq, m, 64);
            }
            float mu  = s * (1.f / 128.f);
            float var = sq * (1.f / 128.f) - mu * mu;
            float rs  = rsqrtf(var + LN_EPS);
            int row = lk8 * 4 + i;
            const int cl = (lrow & 7) * 2;
            #pragma unroll
            for (int n = 0; n < 8; ++n) {
                float w = (u[n] - mu) * rs * g8[n] + bt8[n];
                *(short*)(lds + hbase + tswz(row, n * 2 + (lrow >> 3)) + cl) = f2bf(w);
            }
        }
        asm volatile("s_waitcnt lgkmcnt(0)" ::: "memory");

        // ---- read w in A-layout, residual from registers, coalesced NT store ----
        {
            int row = tile * 16 + lrow;
            if (row < E) {
                float* orow = out + (size_t)row * H_EDGE;
                #pragma unroll
                for (int t = 0; t < 4; ++t) {
                    bf16x8 wf = *(const bf16x8*)(lds + hbase + tswz(lrow, t * 4 + lk8));
                    bf16x8 ef = A1[t + 4];
                    f32x4 lo, hi;
                    lo[0] = bf2f(wf[0]) + bf2f(ef[0]);
                    lo[1] = bf2f(wf[1]) + bf2f(ef[1]);
                    lo[2] = bf2f(wf[2]) + bf2f(ef[2]);
                    lo[3] = bf2f(wf[3]) + bf2f(ef[3]);
                    hi[0] = bf2f(wf[4]) + bf2f(ef[4]);
                    hi[1] = bf2f(wf[5]) + bf2f(ef[5]);
                    hi[2] = bf2f(wf[6]) + bf2f(ef[6]);
                    hi[3] = bf2f(wf[7]) + bf2f(ef[7]);
                    float* dst = orow + t * 32 + lk8 * 8;
                    __builtin_nontemporal_store(lo, (f32x4*)dst);
                    __builtin_nontemporal_store(hi, (f32x4*)(dst + 4));
                }
            }
        }

        // ---- rotate pipeline state ----
        tile = next;  next = t2;
        nrowg = t2rowg; nsidx = t2s; ndidx = t2d;
    }
}

extern "C" void kernel_launch(void* const* d_in, const int* in_sizes, int n_in,
                              void* d_out, int out_size, void* d_ws, size_t ws_size,
                              hipStream_t stream) {
    const float* node  = (const float*)d_in[0];
    const float* edgef = (const float*)d_in[1];
    const int*   ei    = (const int*)d_in[2];    // int32 on device
    const float* W1    = (const float*)d_in[3];
    const float* b1    = (const float*)d_in[4];
    const float* W2    = (const float*)d_in[5];
    const float* b2    = (const float*)d_in[6];
    const float* gamma = (const float*)d_in[7];
    const float* beta  = (const float*)d_in[8];
    float* outp = (float*)d_out;
    const int E = in_sizes[2] / 2;   // edge_index is [2, E]

    hipLaunchKernelGGL(edge_update, dim3(GRID), dim3(BLOCK), 0, stream,
                       node, edgef, ei, W1, b1, W2, b2, gamma, beta, outp, E);
}